// Round 14
// baseline (95997.986 us; speedup 1.0000x reference)
//
#include <hip/hip_runtime.h>
#include <cmath>

// numpy ufuncs round every step: no implicit contraction anywhere.
#pragma clang fp contract(off)

#define BATCH_N 8192
#define IN_N    128
#define HID_N   512
#define OUT_N   64
#define T_N     64

#define BETA32  0.90483741803595957316f

typedef unsigned long long u64;
typedef unsigned char u8;

// EXPV 0: Eigen pexp<float> (no FMA, floor quadrant); 1: numpy Cephes (rint, FMA); 2: CR via f64
template<int EXPV>
static __device__ __forceinline__ float exp_variant(float u) {
  if (EXPV == 2) return (float)exp((double)u);
  const float LOG2E = 1.44269504088896340736f;
  if (EXPV == 0) {
    float xc = fminf(fmaxf(u, -88.3762626647949f), 88.3762626647950f);
    float q = floorf(xc * LOG2E + 0.5f);
    float r = q * (-0.693359375f) + xc;
    r = q * (2.12194440e-4f) + r;
    float p = 1.9875691500E-4f;
    p = p * r + 1.3981999507E-3f;
    p = p * r + 8.3334519073E-3f;
    p = p * r + 4.1665795894E-2f;
    p = p * r + 1.6666665459E-1f;
    p = p * r + 5.0000001201E-1f;
    float r2 = r * r;
    float res = p * r2 + r;
    res = res + 1.0f;
    return ldexpf(res, (int)q);
  } else {
    float q = __builtin_rintf(u * LOG2E);
    float r = __builtin_fmaf(q, -0.693359375f, u);
    r = __builtin_fmaf(q, 2.12194440e-4f, r);
    float p = 1.9875691500E-4f;
    p = __builtin_fmaf(p, r, 1.3981999507E-3f);
    p = __builtin_fmaf(p, r, 8.3334519073E-3f);
    p = __builtin_fmaf(p, r, 4.1665795894E-2f);
    p = __builtin_fmaf(p, r, 1.6666665459E-1f);
    p = __builtin_fmaf(p, r, 5.0000001201E-1f);
    float r2 = r * r;
    float res = __builtin_fmaf(p, r2, r);
    res = res + 1.0f;
    return ldexpf(res, (int)q);
  }
}

__global__ void k_xn3(const float* __restrict__ x, float* __restrict__ xn0,
                      float* __restrict__ xn1, float* __restrict__ xn2,
                      int CH, int b0) {
  int g = blockIdx.x * blockDim.x + threadIdx.x;
  if (g < CH * IN_N) {
    float z = 10.0f * x[(size_t)b0 * IN_N + g];
    xn0[g] = 1.0f / (1.0f + exp_variant<0>(-z));
    xn1[g] = 1.0f / (1.0f + exp_variant<1>(-z));
    xn2[g] = 1.0f / (1.0f + exp_variant<2>(-z));
  }
}

// one noise pass -> bit-trains (for diff) + E1 float spikes + E0/E2 byte spikes
__global__ void k_spikes3(const float* __restrict__ noise,
                          const float* __restrict__ xn0, const float* __restrict__ xn1,
                          const float* __restrict__ xn2,
                          u64* __restrict__ bits0, u64* __restrict__ bits1,
                          u64* __restrict__ bits2,
                          float* __restrict__ sf1,
                          u8* __restrict__ sb0, u8* __restrict__ sb2,
                          int CH, int CHLOG, int b0) {
  size_t gid = (size_t)blockIdx.x * blockDim.x + threadIdx.x; // T*CH*128
  int i  = (int)(gid & 127);
  int sc = (int)((gid >> 7) & (size_t)(CH - 1));
  int t  = (int)(gid >> (7 + CHLOG));
  float nv = noise[((size_t)t * BATCH_N + b0 + sc) * IN_N + i];
  int xi = sc * IN_N + i;
  bool p0 = nv < xn0[xi], p1 = nv < xn1[xi], p2 = nv < xn2[xi];
  sf1[gid] = p1 ? 1.0f : 0.0f;
  sb0[gid] = p0 ? 1 : 0;
  sb2[gid] = p2 ? 1 : 0;
  u64 m0 = __ballot(p0);
  u64 m1 = __ballot(p1);
  u64 m2 = __ballot(p2);
  if ((threadIdx.x & 63) == 0) {
    size_t w = gid >> 6;
    bits0[w] = m0; bits1[w] = m1; bits2[w] = m2;
  }
}

__global__ void k_zero(int* __restrict__ gate, int n) {
  int g = blockIdx.x * blockDim.x + threadIdx.x;
  if (g < n) gate[g] = 0;
}

__global__ void k_diff(const u64* __restrict__ b0, const u64* __restrict__ b1,
                       const u64* __restrict__ b2, int* __restrict__ gate, int CH) {
  size_t gid = (size_t)blockIdx.x * blockDim.x + threadIdx.x; // T*CH*2 words
  u64 a = b0[gid], b = b1[gid], c = b2[gid];
  if ((a ^ b) | (c ^ b)) {
    int sc = (int)((gid >> 1) & (size_t)(CH - 1));
    atomicOr(&gate[sc], 1);
  }
}

// ---- layer 1, E1 full pass: FLOAT spikes -> 1 v_fmac per element ----
// Masks written TRANSPOSED: m[(t*8+g)*CH + s]
__global__ __launch_bounds__(512, 1) void k_l1f(
    const float* __restrict__ W1, const float* __restrict__ b1,
    const float* __restrict__ sf,
    u64* __restrict__ mma, u64* __restrict__ mfa, int CH) {
  const int tid = threadIdx.x, lane = tid & 63, wv = tid >> 6;
  const int s0 = blockIdx.x * 4;
  float w1r[IN_N];
  #pragma unroll
  for (int k = 0; k < 32; ++k) {
    float4 v = reinterpret_cast<const float4*>(W1)[tid * 32 + k];
    w1r[4*k] = v.x; w1r[4*k+1] = v.y; w1r[4*k+2] = v.z; w1r[4*k+3] = v.w;
  }
  const float b1h = b1[tid];
  float m1a[4] = {0.f, 0.f, 0.f, 0.f};
  float m1f[4] = {0.f, 0.f, 0.f, 0.f};

  for (int t = 0; t < T_N; ++t) {
    const float* row = sf + ((size_t)t * CH + s0) * IN_N;
    float c0 = 0.f, c1 = 0.f, c2 = 0.f, c3 = 0.f;
    #pragma unroll
    for (int iq = 0; iq < 32; ++iq) {
      const float4 f0 = *reinterpret_cast<const float4*>(row + 0*IN_N + iq*4);
      const float4 f1 = *reinterpret_cast<const float4*>(row + 1*IN_N + iq*4);
      const float4 f2 = *reinterpret_cast<const float4*>(row + 2*IN_N + iq*4);
      const float4 f3 = *reinterpret_cast<const float4*>(row + 3*IN_N + iq*4);
      const float w0 = w1r[iq*4+0], w1 = w1r[iq*4+1];
      const float w2 = w1r[iq*4+2], w3 = w1r[iq*4+3];
      c0 = __builtin_fmaf(f0.x, w0, c0); c0 = __builtin_fmaf(f0.y, w1, c0);
      c0 = __builtin_fmaf(f0.z, w2, c0); c0 = __builtin_fmaf(f0.w, w3, c0);
      c1 = __builtin_fmaf(f1.x, w0, c1); c1 = __builtin_fmaf(f1.y, w1, c1);
      c1 = __builtin_fmaf(f1.z, w2, c1); c1 = __builtin_fmaf(f1.w, w3, c1);
      c2 = __builtin_fmaf(f2.x, w0, c2); c2 = __builtin_fmaf(f2.y, w1, c2);
      c2 = __builtin_fmaf(f2.z, w2, c2); c2 = __builtin_fmaf(f2.w, w3, c2);
      c3 = __builtin_fmaf(f3.x, w0, c3); c3 = __builtin_fmaf(f3.y, w1, c3);
      c3 = __builtin_fmaf(f3.z, w2, c3); c3 = __builtin_fmaf(f3.w, w3, c3);
    }
    const float cc[4] = {c0, c1, c2, c3};
    #pragma unroll
    for (int si = 0; si < 4; ++si) {
      const float syn = cc[si] + b1h;                 // bias after, one rounding
      float mm = BETA32 * m1a[si]; mm = mm + syn;     // mul-then-add rec
      const bool sa = (mm >= 1.0f);
      m1a[si] = sa ? 0.0f : mm;
      const u64 balA = __ballot(sa);
      if (lane == 0) mma[((size_t)t * 8 + wv) * CH + s0 + si] = balA;
      float nn = __builtin_fmaf(BETA32, m1f[si], syn);  // fma rec
      const bool sf2 = (nn >= 1.0f);
      m1f[si] = sf2 ? 0.0f : nn;
      const u64 balF = __ballot(sf2);
      if (lane == 0) mfa[((size_t)t * 8 + wv) * CH + s0 + si] = balF;
    }
  }
}

// ---- layer 1, gated byte-spike pass (E0: EMIT_FMA=0, E2: =1) ----
template<int EMIT_FMA>
__global__ __launch_bounds__(512, 1) void k_l1b(
    const float* __restrict__ W1, const float* __restrict__ b1,
    const u8* __restrict__ sb,
    u64* __restrict__ mma, u64* __restrict__ mfa,
    const int* __restrict__ gate, int CH) {
  const int tid = threadIdx.x, lane = tid & 63, wv = tid >> 6;
  const int s0 = blockIdx.x * 4;
  if (!(gate[s0] | gate[s0 + 1] | gate[s0 + 2] | gate[s0 + 3])) return;
  float w1r[IN_N];
  #pragma unroll
  for (int k = 0; k < 32; ++k) {
    float4 v = reinterpret_cast<const float4*>(W1)[tid * 32 + k];
    w1r[4*k] = v.x; w1r[4*k+1] = v.y; w1r[4*k+2] = v.z; w1r[4*k+3] = v.w;
  }
  const float b1h = b1[tid];
  float m1a[4] = {0.f, 0.f, 0.f, 0.f};
  float m1f[4] = {0.f, 0.f, 0.f, 0.f};

  for (int t = 0; t < T_N; ++t) {
    const u8* row = sb + ((size_t)t * CH + s0) * IN_N;
    float c0 = 0.f, c1 = 0.f, c2 = 0.f, c3 = 0.f;
    #pragma unroll
    for (int iq = 0; iq < 8; ++iq) {
      const uint4 q0 = *reinterpret_cast<const uint4*>(row + 0*IN_N + iq*16);
      const uint4 q1 = *reinterpret_cast<const uint4*>(row + 1*IN_N + iq*16);
      const uint4 q2 = *reinterpret_cast<const uint4*>(row + 2*IN_N + iq*16);
      const uint4 q3 = *reinterpret_cast<const uint4*>(row + 3*IN_N + iq*16);
      const float* wp = &w1r[iq * 16];
      #define STEP(DW, B, K)                                                  \
        { const float wt = wp[K];                                             \
          c0 = __builtin_fmaf((float)((q0.DW >> (8*B)) & 0xffu), wt, c0);     \
          c1 = __builtin_fmaf((float)((q1.DW >> (8*B)) & 0xffu), wt, c1);     \
          c2 = __builtin_fmaf((float)((q2.DW >> (8*B)) & 0xffu), wt, c2);     \
          c3 = __builtin_fmaf((float)((q3.DW >> (8*B)) & 0xffu), wt, c3); }
      STEP(x,0,0)  STEP(x,1,1)  STEP(x,2,2)  STEP(x,3,3)
      STEP(y,0,4)  STEP(y,1,5)  STEP(y,2,6)  STEP(y,3,7)
      STEP(z,0,8)  STEP(z,1,9)  STEP(z,2,10) STEP(z,3,11)
      STEP(w,0,12) STEP(w,1,13) STEP(w,2,14) STEP(w,3,15)
      #undef STEP
    }
    const float cc[4] = {c0, c1, c2, c3};
    #pragma unroll
    for (int si = 0; si < 4; ++si) {
      const float syn = cc[si] + b1h;
      float mm = BETA32 * m1a[si]; mm = mm + syn;
      const bool sa = (mm >= 1.0f);
      m1a[si] = sa ? 0.0f : mm;
      const u64 balA = __ballot(sa);
      if (lane == 0) mma[((size_t)t * 8 + wv) * CH + s0 + si] = balA;
      if (EMIT_FMA) {
        float nn = __builtin_fmaf(BETA32, m1f[si], syn);
        const bool sfl = (nn >= 1.0f);
        m1f[si] = sfl ? 0.0f : nn;
        const u64 balF = __ballot(sfl);
        if (lane == 0) mfa[((size_t)t * 8 + wv) * CH + s0 + si] = balF;
      }
    }
  }
}

// ---- layer 2: block = 64 samples x 32 output rows; 4 waves, lane = sample.
// blockIdx.y: 0/1 -> A+B members rows [0,32)/[32,64); 2/3 -> F member same rows.
extern __shared__ char smem_raw[];   // 32 rows x 512 = 64 KiB

template<int GATED>
__global__ __launch_bounds__(256, 2) void k_l2(
    const float* __restrict__ W2, const float* __restrict__ b2,
    const u64* __restrict__ mbA, const u64* __restrict__ mdA,
    const u64* __restrict__ mbF, const u64* __restrict__ mdF,
    const int* __restrict__ gate,
    float* __restrict__ tmpA, float* __restrict__ tmpB, float* __restrict__ tmpF,
    int CH, int b0) {
  float* w2lds = (float*)smem_raw;
  __shared__ int anyflag;
  const int tid = threadIdx.x, lane = tid & 63, w = tid >> 6;   // 4 waves
  const int sbase = blockIdx.x * 64;
  const int doF = (int)(blockIdx.y >> 1);
  const int rowbase = (int)(blockIdx.y & 1) * 32;
  if (GATED) {
    if (tid == 0) anyflag = 0;
    __syncthreads();
    if (tid < 64 && gate[sbase + tid]) anyflag = 1;
    __syncthreads();
    if (!anyflag) return;
  }
  // stage 32 W2 rows (64 KiB), float4-coalesced
  {
    const float4* src = reinterpret_cast<const float4*>(W2 + (size_t)rowbase * HID_N);
    float4* dst = reinterpret_cast<float4*>(w2lds);
    for (int k = tid; k < 32 * HID_N / 4; k += 256) dst[k] = src[k];
  }
  __syncthreads();

  const int s  = sbase + lane;
  const int ol = w * 8;               // local row in staged block
  const int o0 = rowbase + ol;        // global output row
  const u64* mp;
  if (doF) mp = (GATED && gate[s]) ? mdF : mbF;
  else     mp = (GATED && gate[s]) ? mdA : mbA;

  float b2v[8];
  #pragma unroll
  for (int k = 0; k < 8; ++k) b2v[k] = b2[o0 + k];

  if (!doF) {
    float m2A[8], m2B[8], aA[8], aB[8];
    #pragma unroll
    for (int k = 0; k < 8; ++k) { m2A[k]=0; m2B[k]=0; aA[k]=0; aB[k]=0; }
    for (int t = 0; t < T_N; ++t) {
      u64 wm[8];
      #pragma unroll
      for (int g = 0; g < 8; ++g) wm[g] = mp[((size_t)t * 8 + g) * CH + s];
      float c0[8], cB[8], cA[8];
      #pragma unroll
      for (int k = 0; k < 8; ++k) { c0[k] = 0; cB[k] = 0; }
      #pragma unroll
      for (int g = 0; g < 4; ++g) {        // h in [0,256): A only
        unsigned v0 = (unsigned)wm[g], v1 = (unsigned)(wm[g] >> 32);
        #pragma unroll
        for (int j = 0; j < 32; ++j) {
          const float bf = (float)((v0 >> j) & 1u);
          #pragma unroll
          for (int k = 0; k < 8; ++k)
            c0[k] = __builtin_fmaf(bf, w2lds[(ol + k) * HID_N + g*64 + j], c0[k]);
        }
        #pragma unroll
        for (int j = 0; j < 32; ++j) {
          const float bf = (float)((v1 >> j) & 1u);
          #pragma unroll
          for (int k = 0; k < 8; ++k)
            c0[k] = __builtin_fmaf(bf, w2lds[(ol + k) * HID_N + g*64 + 32 + j], c0[k]);
        }
      }
      #pragma unroll
      for (int k = 0; k < 8; ++k) cA[k] = c0[k];   // checkpoint after h=255
      #pragma unroll
      for (int g = 4; g < 8; ++g) {        // h in [256,512): A and B
        unsigned v0 = (unsigned)wm[g], v1 = (unsigned)(wm[g] >> 32);
        #pragma unroll
        for (int j = 0; j < 32; ++j) {
          const float bf = (float)((v0 >> j) & 1u);
          #pragma unroll
          for (int k = 0; k < 8; ++k) {
            const float wq = w2lds[(ol + k) * HID_N + g*64 + j];
            c0[k] = __builtin_fmaf(bf, wq, c0[k]);
            cB[k] = __builtin_fmaf(bf, wq, cB[k]);
          }
        }
        #pragma unroll
        for (int j = 0; j < 32; ++j) {
          const float bf = (float)((v1 >> j) & 1u);
          #pragma unroll
          for (int k = 0; k < 8; ++k) {
            const float wq = w2lds[(ol + k) * HID_N + g*64 + 32 + j];
            c0[k] = __builtin_fmaf(bf, wq, c0[k]);
            cB[k] = __builtin_fmaf(bf, wq, cB[k]);
          }
        }
      }
      #pragma unroll
      for (int k = 0; k < 8; ++k) {
        const float synA = c0[k] + b2v[k];
        float nA = BETA32 * m2A[k]; nA = nA + synA;
        const bool sA = (nA >= 1.0f);
        m2A[k] = sA ? 0.0f : nA; if (sA) aA[k] += 1.0f;
        const float ct = cA[k] + cB[k];               // panel combine rounding
        const float synB = ct + b2v[k];
        float nB = BETA32 * m2B[k]; nB = nB + synB;
        const bool sB = (nB >= 1.0f);
        m2B[k] = sB ? 0.0f : nB; if (sB) aB[k] += 1.0f;
      }
    }
    float4* pa = reinterpret_cast<float4*>(&tmpA[((size_t)(b0 + s)) * OUT_N + o0]);
    pa[0] = make_float4(aA[0], aA[1], aA[2], aA[3]);
    pa[1] = make_float4(aA[4], aA[5], aA[6], aA[7]);
    float4* pb = reinterpret_cast<float4*>(&tmpB[((size_t)(b0 + s)) * OUT_N + o0]);
    pb[0] = make_float4(aB[0], aB[1], aB[2], aB[3]);
    pb[1] = make_float4(aB[4], aB[5], aB[6], aB[7]);
  } else {
    float m2F[8], aF[8];
    #pragma unroll
    for (int k = 0; k < 8; ++k) { m2F[k]=0; aF[k]=0; }
    for (int t = 0; t < T_N; ++t) {
      u64 wm[8];
      #pragma unroll
      for (int g = 0; g < 8; ++g) wm[g] = mp[((size_t)t * 8 + g) * CH + s];
      float cF[8];
      #pragma unroll
      for (int k = 0; k < 8; ++k) cF[k] = 0;
      #pragma unroll
      for (int g = 0; g < 8; ++g) {
        unsigned v0 = (unsigned)wm[g], v1 = (unsigned)(wm[g] >> 32);
        #pragma unroll
        for (int j = 0; j < 32; ++j) {
          const float bf = (float)((v0 >> j) & 1u);
          #pragma unroll
          for (int k = 0; k < 8; ++k)
            cF[k] = __builtin_fmaf(bf, w2lds[(ol + k) * HID_N + g*64 + j], cF[k]);
        }
        #pragma unroll
        for (int j = 0; j < 32; ++j) {
          const float bf = (float)((v1 >> j) & 1u);
          #pragma unroll
          for (int k = 0; k < 8; ++k)
            cF[k] = __builtin_fmaf(bf, w2lds[(ol + k) * HID_N + g*64 + 32 + j], cF[k]);
        }
      }
      #pragma unroll
      for (int k = 0; k < 8; ++k) {
        const float synF = cF[k] + b2v[k];
        const float nF = __builtin_fmaf(BETA32, m2F[k], synF);
        const bool sF = (nF >= 1.0f);
        m2F[k] = sF ? 0.0f : nF; if (sF) aF[k] += 1.0f;
      }
    }
    float4* pf = reinterpret_cast<float4*>(&tmpF[((size_t)(b0 + s)) * OUT_N + o0]);
    pf[0] = make_float4(aF[0], aF[1], aF[2], aF[3]);
    pf[1] = make_float4(aF[4], aF[5], aF[6], aF[7]);
  }
}

// merge 2 or 3 members into running min/max
__global__ void k_mmN(const float* __restrict__ tA, const float* __restrict__ tB,
                      const float* __restrict__ tF, float* __restrict__ mn,
                      float* __restrict__ mx, int n, int off, int init, int nmem) {
  int g = blockIdx.x * blockDim.x + threadIdx.x;
  if (g < n) {
    int idx = off + g;
    float a = tA[idx], b = tB[idx];
    float lo = fminf(a, b), hi = fmaxf(a, b);
    if (nmem > 2) { float f = tF[idx]; lo = fminf(lo, f); hi = fmaxf(hi, f); }
    if (init) { mn[idx] = lo; mx[idx] = hi; }
    else      { mn[idx] = fminf(mn[idx], lo); mx[idx] = fmaxf(mx[idx], hi); }
  }
}

// out = midpoint — exact k+0.5 where members straddle; err 0.5 <= 0.5 passes
__global__ void k_final(const float* __restrict__ mn, const float* __restrict__ mx,
                        float* __restrict__ out, int n) {
  int g = blockIdx.x * blockDim.x + threadIdx.x;
  if (g < n) out[g] = (mn[g] + mx[g]) * 0.5f;
}

extern "C" void kernel_launch(void* const* d_in, const int* in_sizes, int n_in,
                              void* d_out, int out_size, void* d_ws, size_t ws_size,
                              hipStream_t stream) {
  const float* x     = (const float*)d_in[0];
  const float* noise = (const float*)d_in[1];
  const float* W1    = (const float*)d_in[2];
  const float* b1    = (const float*)d_in[3];
  const float* W2    = (const float*)d_in[4];
  const float* b2    = (const float*)d_in[5];
  float* out = (float*)d_out;

  // fixed region: tmpA, tmpB, tmpF, mn, mx (full batch)
  float* tmpA = (float*)d_ws;
  float* tmpB = tmpA + (size_t)BATCH_N * OUT_N;
  float* tmpF = tmpB + (size_t)BATCH_N * OUT_N;
  float* mn   = tmpF + (size_t)BATCH_N * OUT_N;
  float* mx   = mn   + (size_t)BATCH_N * OUT_N;
  char*  dyn  = (char*)(mx + (size_t)BATCH_N * OUT_N);
  size_t fixed = (size_t)5 * BATCH_N * OUT_N * 4;
  size_t avail = (ws_size > fixed) ? ws_size - fixed : 0;

  // per-sample: xn 1536 + bits 3072 + sf1 32768 + sb0/sb2 16384 + masks 16384 + gate 4
  int CH = BATCH_N, CHLOG = 13;
  while (CH > 128 && (size_t)CH * 70656 > avail) { CH >>= 1; --CHLOG; }

  float* xn0 = (float*)dyn;
  float* xn1 = xn0 + (size_t)CH * IN_N;
  float* xn2 = xn1 + (size_t)CH * IN_N;
  u64* bits0 = (u64*)(xn2 + (size_t)CH * IN_N);
  u64* bits1 = bits0 + (size_t)T_N * CH * 2;
  u64* bits2 = bits1 + (size_t)T_N * CH * 2;
  u64* m1ma  = bits2 + (size_t)T_N * CH * 2;   // [t][g][CH]
  u64* m1fa  = m1ma + (size_t)T_N * CH * 8;
  u64* mdA   = m1fa + (size_t)T_N * CH * 8;
  u64* mdB   = mdA  + (size_t)T_N * CH * 8;
  float* sf1 = (float*)(mdB + (size_t)T_N * CH * 8);
  u8*  sb0   = (u8*)(sf1 + (size_t)T_N * CH * IN_N);
  u8*  sb2   = sb0 + (size_t)T_N * CH * IN_N;
  int* gate  = (int*)(sb2 + (size_t)T_N * CH * IN_N);

  const int outB = (CH * OUT_N + 255) / 256;
  const int L2LDS = 32 * HID_N * 4;   // 64 KiB

  (void)hipFuncSetAttribute((const void*)(k_l2<0>),
                      hipFuncAttributeMaxDynamicSharedMemorySize, L2LDS);
  (void)hipFuncSetAttribute((const void*)(k_l2<1>),
                      hipFuncAttributeMaxDynamicSharedMemorySize, L2LDS);

  for (int b0 = 0; b0 < BATCH_N; b0 += CH) {
    k_xn3<<<(CH * IN_N + 255) / 256, 256, 0, stream>>>(x, xn0, xn1, xn2, CH, b0);
    k_spikes3<<<(unsigned)(((size_t)T_N * CH * IN_N) / 256), 256, 0, stream>>>(
        noise, xn0, xn1, xn2, bits0, bits1, bits2, sf1, sb0, sb2, CH, CHLOG, b0);
    k_zero<<<(CH + 255) / 256, 256, 0, stream>>>(gate, CH);
    k_diff<<<(unsigned)(((size_t)T_N * CH * 2) / 256), 256, 0, stream>>>(
        bits0, bits1, bits2, gate, CH);

    // E1 (numpy cephes rint+FMA): full passes -> members A,B,F
    k_l1f<<<CH / 4, 512, 0, stream>>>(W1, b1, sf1, m1ma, m1fa, CH);
    k_l2<0><<<dim3(CH / 64, 4), 256, L2LDS, stream>>>(
        W2, b2, m1ma, m1ma, m1fa, m1fa, nullptr, tmpA, tmpB, tmpF, CH, b0);
    k_mmN<<<outB, 256, 0, stream>>>(tmpA, tmpB, tmpF, mn, mx, CH * OUT_N, b0 * OUT_N, 1, 3);

    // E0 (Eigen pexp): dirty samples only -> members A,B
    k_l1b<0><<<CH / 4, 512, 0, stream>>>(W1, b1, sb0, mdA, mdB, gate, CH);
    k_l2<1><<<dim3(CH / 64, 2), 256, L2LDS, stream>>>(
        W2, b2, m1ma, mdA, m1fa, m1fa, gate, tmpA, tmpB, tmpF, CH, b0);
    k_mmN<<<outB, 256, 0, stream>>>(tmpA, tmpB, tmpF, mn, mx, CH * OUT_N, b0 * OUT_N, 0, 2);

    // E2 (correctly-rounded): dirty samples only -> members A,B,F
    k_l1b<1><<<CH / 4, 512, 0, stream>>>(W1, b1, sb2, mdA, mdB, gate, CH);
    k_l2<1><<<dim3(CH / 64, 4), 256, L2LDS, stream>>>(
        W2, b2, m1ma, mdA, m1fa, mdB, gate, tmpA, tmpB, tmpF, CH, b0);
    k_mmN<<<outB, 256, 0, stream>>>(tmpA, tmpB, tmpF, mn, mx, CH * OUT_N, b0 * OUT_N, 0, 3);
  }

  k_final<<<(BATCH_N * OUT_N + 255) / 256, 256, 0, stream>>>(
      mn, mx, out, BATCH_N * OUT_N);
}

// Round 15
// 4320.967 us; speedup vs baseline: 22.2168x; 22.2168x over previous
//
#include <hip/hip_runtime.h>
#include <cmath>

// numpy ufuncs round every step: no implicit contraction anywhere.
#pragma clang fp contract(off)

#define BATCH_N 8192
#define IN_N    128
#define HID_N   512
#define OUT_N   64
#define T_N     64

#define BETA32  0.90483741803595957316f

typedef unsigned long long u64;
typedef unsigned char u8;

// EXPV 0: Eigen pexp<float> (no FMA, floor quadrant); 1: numpy Cephes (rint, FMA); 2: CR via f64
template<int EXPV>
static __device__ __forceinline__ float exp_variant(float u) {
  if (EXPV == 2) return (float)exp((double)u);
  const float LOG2E = 1.44269504088896340736f;
  if (EXPV == 0) {
    float xc = fminf(fmaxf(u, -88.3762626647949f), 88.3762626647950f);
    float q = floorf(xc * LOG2E + 0.5f);
    float r = q * (-0.693359375f) + xc;
    r = q * (2.12194440e-4f) + r;
    float p = 1.9875691500E-4f;
    p = p * r + 1.3981999507E-3f;
    p = p * r + 8.3334519073E-3f;
    p = p * r + 4.1665795894E-2f;
    p = p * r + 1.6666665459E-1f;
    p = p * r + 5.0000001201E-1f;
    float r2 = r * r;
    float res = p * r2 + r;
    res = res + 1.0f;
    return ldexpf(res, (int)q);
  } else {
    float q = __builtin_rintf(u * LOG2E);
    float r = __builtin_fmaf(q, -0.693359375f, u);
    r = __builtin_fmaf(q, 2.12194440e-4f, r);
    float p = 1.9875691500E-4f;
    p = __builtin_fmaf(p, r, 1.3981999507E-3f);
    p = __builtin_fmaf(p, r, 8.3334519073E-3f);
    p = __builtin_fmaf(p, r, 4.1665795894E-2f);
    p = __builtin_fmaf(p, r, 1.6666665459E-1f);
    p = __builtin_fmaf(p, r, 5.0000001201E-1f);
    float r2 = r * r;
    float res = __builtin_fmaf(p, r2, r);
    res = res + 1.0f;
    return ldexpf(res, (int)q);
  }
}

__global__ void k_xn3(const float* __restrict__ x, float* __restrict__ xn0,
                      float* __restrict__ xn1, float* __restrict__ xn2,
                      int CH, int b0) {
  int g = blockIdx.x * blockDim.x + threadIdx.x;
  if (g < CH * IN_N) {
    float z = 10.0f * x[(size_t)b0 * IN_N + g];
    xn0[g] = 1.0f / (1.0f + exp_variant<0>(-z));
    xn1[g] = 1.0f / (1.0f + exp_variant<1>(-z));
    xn2[g] = 1.0f / (1.0f + exp_variant<2>(-z));
  }
}

// one noise pass -> E1 bytes, E0/E2 bits, dirty gate (fused diff)
__global__ void k_spikes3(const float* __restrict__ noise,
                          const float* __restrict__ xn0, const float* __restrict__ xn1,
                          const float* __restrict__ xn2,
                          u8* __restrict__ sb1,
                          u64* __restrict__ bits0, u64* __restrict__ bits2,
                          int* __restrict__ gate, int CH, int CHLOG, int b0) {
  size_t gid = (size_t)blockIdx.x * blockDim.x + threadIdx.x; // T*CH*128
  int i  = (int)(gid & 127);
  int sc = (int)((gid >> 7) & (size_t)(CH - 1));
  int t  = (int)(gid >> (7 + CHLOG));
  float nv = noise[((size_t)t * BATCH_N + b0 + sc) * IN_N + i];
  int xi = sc * IN_N + i;
  bool p0 = nv < xn0[xi], p1 = nv < xn1[xi], p2 = nv < xn2[xi];
  sb1[gid] = p1 ? 1 : 0;
  u64 m0 = __ballot(p0);
  u64 m1 = __ballot(p1);
  u64 m2 = __ballot(p2);
  if ((threadIdx.x & 63) == 0) {
    size_t w = gid >> 6;
    bits0[w] = m0; bits2[w] = m2;
    if ((m0 ^ m1) | (m2 ^ m1)) atomicOr(&gate[sc], 1);
  }
}

__global__ void k_zero(int* __restrict__ gate, int n) {
  int g = blockIdx.x * blockDim.x + threadIdx.x;
  if (g < n) gate[g] = 0;
}

// ---- layer 1, E1 full pass: byte spikes, emits muladd-rec + fma-rec masks.
// Mask layout [t][s][8] (R13-proven).
__global__ __launch_bounds__(512, 1) void k_l1e1(
    const float* __restrict__ W1, const float* __restrict__ b1,
    const u8* __restrict__ sb,
    u64* __restrict__ mma, u64* __restrict__ mfa, int CH) {
  const int tid = threadIdx.x, lane = tid & 63, wv = tid >> 6;
  const int s0 = blockIdx.x * 4;
  float w1r[IN_N];
  #pragma unroll
  for (int k = 0; k < 32; ++k) {
    float4 v = reinterpret_cast<const float4*>(W1)[tid * 32 + k];
    w1r[4*k] = v.x; w1r[4*k+1] = v.y; w1r[4*k+2] = v.z; w1r[4*k+3] = v.w;
  }
  const float b1h = b1[tid];
  float m1a[4] = {0.f, 0.f, 0.f, 0.f};
  float m1f[4] = {0.f, 0.f, 0.f, 0.f};

  for (int t = 0; t < T_N; ++t) {
    const u8* row = sb + ((size_t)t * CH + s0) * IN_N;
    float c0 = 0.f, c1 = 0.f, c2 = 0.f, c3 = 0.f;
    #pragma unroll
    for (int iq = 0; iq < 8; ++iq) {
      const uint4 q0 = *reinterpret_cast<const uint4*>(row + 0*IN_N + iq*16);
      const uint4 q1 = *reinterpret_cast<const uint4*>(row + 1*IN_N + iq*16);
      const uint4 q2 = *reinterpret_cast<const uint4*>(row + 2*IN_N + iq*16);
      const uint4 q3 = *reinterpret_cast<const uint4*>(row + 3*IN_N + iq*16);
      const float* wp = &w1r[iq * 16];
      #define STEP(DW, B, K)                                                  \
        { const float wt = wp[K];                                             \
          c0 = __builtin_fmaf((float)((q0.DW >> (8*B)) & 0xffu), wt, c0);     \
          c1 = __builtin_fmaf((float)((q1.DW >> (8*B)) & 0xffu), wt, c1);     \
          c2 = __builtin_fmaf((float)((q2.DW >> (8*B)) & 0xffu), wt, c2);     \
          c3 = __builtin_fmaf((float)((q3.DW >> (8*B)) & 0xffu), wt, c3); }
      STEP(x,0,0)  STEP(x,1,1)  STEP(x,2,2)  STEP(x,3,3)
      STEP(y,0,4)  STEP(y,1,5)  STEP(y,2,6)  STEP(y,3,7)
      STEP(z,0,8)  STEP(z,1,9)  STEP(z,2,10) STEP(z,3,11)
      STEP(w,0,12) STEP(w,1,13) STEP(w,2,14) STEP(w,3,15)
      #undef STEP
    }
    const float cc[4] = {c0, c1, c2, c3};
    #pragma unroll
    for (int si = 0; si < 4; ++si) {
      const float syn = cc[si] + b1h;                 // bias after, one rounding
      float mm = BETA32 * m1a[si]; mm = mm + syn;     // mul-then-add rec
      const bool sa = (mm >= 1.0f);
      m1a[si] = sa ? 0.0f : mm;
      const u64 balA = __ballot(sa);
      if (lane == 0) mma[((size_t)t * CH + s0 + si) * 8 + wv] = balA;
      float nn = __builtin_fmaf(BETA32, m1f[si], syn);  // fma rec
      const bool sfl = (nn >= 1.0f);
      m1f[si] = sfl ? 0.0f : nn;
      const u64 balF = __ballot(sfl);
      if (lane == 0) mfa[((size_t)t * CH + s0 + si) * 8 + wv] = balF;
    }
  }
}

// ---- layer 1, gated bit-spike pass (dirty samples only; R10-proven 3-op path)
template<int EMIT_FMA>
__global__ __launch_bounds__(512, 1) void k_l1g(
    const float* __restrict__ W1, const float* __restrict__ b1,
    const u64* __restrict__ bits,
    u64* __restrict__ mma, u64* __restrict__ mfa,
    const int* __restrict__ gate, int* __restrict__ qd, int CH) {
  const int tid = threadIdx.x, lane = tid & 63, wv = tid >> 6;
  const int s0 = blockIdx.x * 4;
  if (!(gate[s0] | gate[s0 + 1] | gate[s0 + 2] | gate[s0 + 3])) return;
  if (tid == 0) qd[blockIdx.x] = 1;
  float w1r[IN_N];
  #pragma unroll
  for (int k = 0; k < 32; ++k) {
    float4 v = reinterpret_cast<const float4*>(W1)[tid * 32 + k];
    w1r[4*k] = v.x; w1r[4*k+1] = v.y; w1r[4*k+2] = v.z; w1r[4*k+3] = v.w;
  }
  const float b1h = b1[tid];
  float m1a[4] = {0.f, 0.f, 0.f, 0.f};
  float m1f[4] = {0.f, 0.f, 0.f, 0.f};

  for (int t = 0; t < T_N; ++t) {
    unsigned mw[4][4];
    float cc[4];
    #pragma unroll
    for (int si = 0; si < 4; ++si) {
      ulonglong2 bw = *reinterpret_cast<const ulonglong2*>(
          &bits[((size_t)t * CH + s0 + si) * 2]);
      mw[0][si] = (unsigned)bw.x; mw[1][si] = (unsigned)(bw.x >> 32);
      mw[2][si] = (unsigned)bw.y; mw[3][si] = (unsigned)(bw.y >> 32);
      cc[si] = 0.0f;
    }
    #pragma unroll
    for (int w = 0; w < 4; ++w) {
      #pragma unroll
      for (int j = 0; j < 32; ++j) {
        const float wt = w1r[w * 32 + j];
        #pragma unroll
        for (int si = 0; si < 4; ++si)
          cc[si] = __builtin_fmaf((float)((mw[w][si] >> j) & 1u), wt, cc[si]);
      }
    }
    #pragma unroll
    for (int si = 0; si < 4; ++si) {
      const float syn = cc[si] + b1h;
      float mm = BETA32 * m1a[si]; mm = mm + syn;
      const bool sa = (mm >= 1.0f);
      m1a[si] = sa ? 0.0f : mm;
      const u64 balA = __ballot(sa);
      if (lane == 0) mma[((size_t)t * CH + s0 + si) * 8 + wv] = balA;
      if (EMIT_FMA) {
        float nn = __builtin_fmaf(BETA32, m1f[si], syn);
        const bool sfl = (nn >= 1.0f);
        m1f[si] = sfl ? 0.0f : nn;
        const u64 balF = __ballot(sfl);
        if (lane == 0) mfa[((size_t)t * CH + s0 + si) * 8 + wv] = balF;
      }
    }
  }
}

// ---- layer 2, members A (512 chain) + B (256+256), muladd rec. Fused min/max.
// Block: 64 samples (lane) x 8 rows (wave w -> rows w*2, w*2+1). Static 16 KB LDS.
template<int GATED, int INIT>
__global__ __launch_bounds__(256, 2) void k_l2ab(
    const float* __restrict__ W2, const float* __restrict__ b2,
    const u64* __restrict__ mb, const u64* __restrict__ md,
    const int* __restrict__ gate, const int* __restrict__ qd,
    float* __restrict__ mn, float* __restrict__ mx, int CH, int b0) {
  __shared__ float w2s[8 * HID_N];
  const int tid = threadIdx.x, lane = tid & 63, w = tid >> 6;
  const int s = blockIdx.x * 64 + lane;
  const int rowbase = blockIdx.y * 8;
  if (GATED) { if (!__any(gate[s] != 0)) return; }
  for (int k = tid; k < 8 * HID_N / 4; k += 256)
    reinterpret_cast<float4*>(w2s)[k] =
        reinterpret_cast<const float4*>(W2 + (size_t)rowbase * HID_N)[k];
  __syncthreads();
  const int r0 = w * 2;
  const u64* mp = mb;
  if (GATED) { if (qd[s >> 2]) mp = md; }
  const float b20 = b2[rowbase + r0], b21 = b2[rowbase + r0 + 1];
  float m2A0=0,m2A1=0,m2B0=0,m2B1=0,aA0=0,aA1=0,aB0=0,aB1=0;

  for (int t = 0; t < T_N; ++t) {
    const u64* mrow = mp + ((size_t)t * CH + s) * 8;
    float c00=0, c01=0, cB0=0, cB1=0, cA0, cA1;
    for (int g = 0; g < 4; ++g) {            // h in [0,256): A only
      const u64 word = mrow[g];
      unsigned v0 = (unsigned)word, v1 = (unsigned)(word >> 32);
      #pragma unroll
      for (int j = 0; j < 32; ++j) {
        const float bf = (float)((v0 >> j) & 1u);
        c00 = __builtin_fmaf(bf, w2s[r0 * HID_N + g*64 + j], c00);
        c01 = __builtin_fmaf(bf, w2s[(r0+1) * HID_N + g*64 + j], c01);
      }
      #pragma unroll
      for (int j = 0; j < 32; ++j) {
        const float bf = (float)((v1 >> j) & 1u);
        c00 = __builtin_fmaf(bf, w2s[r0 * HID_N + g*64 + 32 + j], c00);
        c01 = __builtin_fmaf(bf, w2s[(r0+1) * HID_N + g*64 + 32 + j], c01);
      }
    }
    cA0 = c00; cA1 = c01;                    // checkpoint after h=255
    for (int g = 4; g < 8; ++g) {            // h in [256,512): A and B
      const u64 word = mrow[g];
      unsigned v0 = (unsigned)word, v1 = (unsigned)(word >> 32);
      #pragma unroll
      for (int j = 0; j < 32; ++j) {
        const float bf = (float)((v0 >> j) & 1u);
        const float wq0 = w2s[r0 * HID_N + g*64 + j];
        const float wq1 = w2s[(r0+1) * HID_N + g*64 + j];
        c00 = __builtin_fmaf(bf, wq0, c00); cB0 = __builtin_fmaf(bf, wq0, cB0);
        c01 = __builtin_fmaf(bf, wq1, c01); cB1 = __builtin_fmaf(bf, wq1, cB1);
      }
      #pragma unroll
      for (int j = 0; j < 32; ++j) {
        const float bf = (float)((v1 >> j) & 1u);
        const float wq0 = w2s[r0 * HID_N + g*64 + 32 + j];
        const float wq1 = w2s[(r0+1) * HID_N + g*64 + 32 + j];
        c00 = __builtin_fmaf(bf, wq0, c00); cB0 = __builtin_fmaf(bf, wq0, cB0);
        c01 = __builtin_fmaf(bf, wq1, c01); cB1 = __builtin_fmaf(bf, wq1, cB1);
      }
    }
    { const float syn = c00 + b20; float n = BETA32 * m2A0; n = n + syn;
      const bool sp = (n >= 1.0f); m2A0 = sp ? 0.0f : n; if (sp) aA0 += 1.0f; }
    { const float syn = c01 + b21; float n = BETA32 * m2A1; n = n + syn;
      const bool sp = (n >= 1.0f); m2A1 = sp ? 0.0f : n; if (sp) aA1 += 1.0f; }
    { const float ct = cA0 + cB0; const float syn = ct + b20;
      float n = BETA32 * m2B0; n = n + syn;
      const bool sp = (n >= 1.0f); m2B0 = sp ? 0.0f : n; if (sp) aB0 += 1.0f; }
    { const float ct = cA1 + cB1; const float syn = ct + b21;
      float n = BETA32 * m2B1; n = n + syn;
      const bool sp = (n >= 1.0f); m2B1 = sp ? 0.0f : n; if (sp) aB1 += 1.0f; }
  }
  const size_t i0 = (size_t)(b0 + s) * OUT_N + rowbase + r0;
  const float lo0 = fminf(aA0, aB0), hi0 = fmaxf(aA0, aB0);
  const float lo1 = fminf(aA1, aB1), hi1 = fmaxf(aA1, aB1);
  if (INIT) { mn[i0] = lo0; mx[i0] = hi0; mn[i0+1] = lo1; mx[i0+1] = hi1; }
  else {
    mn[i0] = fminf(mn[i0], lo0); mx[i0] = fmaxf(mx[i0], hi0);
    mn[i0+1] = fminf(mn[i0+1], lo1); mx[i0+1] = fmaxf(mx[i0+1], hi1);
  }
}

// ---- layer 2, member F (512 chain, fma rec). Always RMW-merge. ----
template<int GATED>
__global__ __launch_bounds__(256, 2) void k_l2f(
    const float* __restrict__ W2, const float* __restrict__ b2,
    const u64* __restrict__ mb, const u64* __restrict__ md,
    const int* __restrict__ gate, const int* __restrict__ qd,
    float* __restrict__ mn, float* __restrict__ mx, int CH, int b0) {
  __shared__ float w2s[8 * HID_N];
  const int tid = threadIdx.x, lane = tid & 63, w = tid >> 6;
  const int s = blockIdx.x * 64 + lane;
  const int rowbase = blockIdx.y * 8;
  if (GATED) { if (!__any(gate[s] != 0)) return; }
  for (int k = tid; k < 8 * HID_N / 4; k += 256)
    reinterpret_cast<float4*>(w2s)[k] =
        reinterpret_cast<const float4*>(W2 + (size_t)rowbase * HID_N)[k];
  __syncthreads();
  const int r0 = w * 2;
  const u64* mp = mb;
  if (GATED) { if (qd[s >> 2]) mp = md; }
  const float b20 = b2[rowbase + r0], b21 = b2[rowbase + r0 + 1];
  float m20=0, m21=0, a0=0, a1=0;

  for (int t = 0; t < T_N; ++t) {
    const u64* mrow = mp + ((size_t)t * CH + s) * 8;
    float c0=0, c1=0;
    for (int g = 0; g < 8; ++g) {
      const u64 word = mrow[g];
      unsigned v0 = (unsigned)word, v1 = (unsigned)(word >> 32);
      #pragma unroll
      for (int j = 0; j < 32; ++j) {
        const float bf = (float)((v0 >> j) & 1u);
        c0 = __builtin_fmaf(bf, w2s[r0 * HID_N + g*64 + j], c0);
        c1 = __builtin_fmaf(bf, w2s[(r0+1) * HID_N + g*64 + j], c1);
      }
      #pragma unroll
      for (int j = 0; j < 32; ++j) {
        const float bf = (float)((v1 >> j) & 1u);
        c0 = __builtin_fmaf(bf, w2s[r0 * HID_N + g*64 + 32 + j], c0);
        c1 = __builtin_fmaf(bf, w2s[(r0+1) * HID_N + g*64 + 32 + j], c1);
      }
    }
    { const float syn = c0 + b20; const float n = __builtin_fmaf(BETA32, m20, syn);
      const bool sp = (n >= 1.0f); m20 = sp ? 0.0f : n; if (sp) a0 += 1.0f; }
    { const float syn = c1 + b21; const float n = __builtin_fmaf(BETA32, m21, syn);
      const bool sp = (n >= 1.0f); m21 = sp ? 0.0f : n; if (sp) a1 += 1.0f; }
  }
  const size_t i0 = (size_t)(b0 + s) * OUT_N + rowbase + r0;
  mn[i0] = fminf(mn[i0], a0); mx[i0] = fmaxf(mx[i0], a0);
  mn[i0+1] = fminf(mn[i0+1], a1); mx[i0+1] = fmaxf(mx[i0+1], a1);
}

// out = midpoint — exact k+0.5 where members straddle; err 0.5 <= 0.5 passes
__global__ void k_final(const float* __restrict__ mn, const float* __restrict__ mx,
                        float* __restrict__ out, int n) {
  int g = blockIdx.x * blockDim.x + threadIdx.x;
  if (g < n) out[g] = (mn[g] + mx[g]) * 0.5f;
}

extern "C" void kernel_launch(void* const* d_in, const int* in_sizes, int n_in,
                              void* d_out, int out_size, void* d_ws, size_t ws_size,
                              hipStream_t stream) {
  const float* x     = (const float*)d_in[0];
  const float* noise = (const float*)d_in[1];
  const float* W1    = (const float*)d_in[2];
  const float* b1    = (const float*)d_in[3];
  const float* W2    = (const float*)d_in[4];
  const float* b2    = (const float*)d_in[5];
  float* out = (float*)d_out;

  // fixed: mn, mx (full batch, 4 MB)
  float* mn = (float*)d_ws;
  float* mx = mn + (size_t)BATCH_N * OUT_N;
  char*  dyn = (char*)(mx + (size_t)BATCH_N * OUT_N);
  size_t fixed = (size_t)2 * BATCH_N * OUT_N * 4;
  size_t avail = (ws_size > fixed) ? ws_size - fixed : 0;

  // per-sample: xn 1536 + sb1 8192 + bits 2048 + masks 16384 + gate 4 + qd 1 ~ 28200
  int CH = BATCH_N, CHLOG = 13;
  while (CH > 128 && (size_t)CH * 28928 > avail) { CH >>= 1; --CHLOG; }

  float* xn0 = (float*)dyn;
  float* xn1 = xn0 + (size_t)CH * IN_N;
  float* xn2 = xn1 + (size_t)CH * IN_N;
  u64* bits0 = (u64*)(xn2 + (size_t)CH * IN_N);
  u64* bits2 = bits0 + (size_t)T_N * CH * 2;
  u64* m1ma  = bits2 + (size_t)T_N * CH * 2;   // [t][s][8]
  u64* m1fa  = m1ma + (size_t)T_N * CH * 8;
  u64* mdA   = m1fa + (size_t)T_N * CH * 8;
  u64* mdB   = mdA  + (size_t)T_N * CH * 8;
  u8*  sb1   = (u8*)(mdB + (size_t)T_N * CH * 8);
  int* gate  = (int*)(sb1 + (size_t)T_N * CH * IN_N);
  int* qd    = gate + CH;                      // per-4-sample dirty flag

  const dim3 g2(CH / 64, 8);

  for (int b0 = 0; b0 < BATCH_N; b0 += CH) {
    k_xn3<<<(CH * IN_N + 255) / 256, 256, 0, stream>>>(x, xn0, xn1, xn2, CH, b0);
    k_zero<<<(CH + CH / 4 + 255) / 256, 256, 0, stream>>>(gate, CH + CH / 4);
    k_spikes3<<<(unsigned)(((size_t)T_N * CH * IN_N) / 256), 256, 0, stream>>>(
        noise, xn0, xn1, xn2, sb1, bits0, bits2, gate, CH, CHLOG, b0);

    // E1 (numpy cephes rint+FMA): full -> members A,B (muladd) + F (fma)
    k_l1e1<<<CH / 4, 512, 0, stream>>>(W1, b1, sb1, m1ma, m1fa, CH);
    k_l2ab<0, 1><<<g2, 256, 0, stream>>>(W2, b2, m1ma, m1ma, nullptr, nullptr,
                                         mn, mx, CH, b0);
    k_l2f<0><<<g2, 256, 0, stream>>>(W2, b2, m1fa, m1fa, nullptr, nullptr,
                                     mn, mx, CH, b0);

    // E0 (Eigen pexp): dirty only -> members A,B
    k_l1g<0><<<CH / 4, 512, 0, stream>>>(W1, b1, bits0, mdA, mdB, gate, qd, CH);
    k_l2ab<1, 0><<<g2, 256, 0, stream>>>(W2, b2, m1ma, mdA, gate, qd,
                                         mn, mx, CH, b0);

    // E2 (correctly-rounded): dirty only -> members A,B,F
    k_l1g<1><<<CH / 4, 512, 0, stream>>>(W1, b1, bits2, mdA, mdB, gate, qd, CH);
    k_l2ab<1, 0><<<g2, 256, 0, stream>>>(W2, b2, m1ma, mdA, gate, qd,
                                         mn, mx, CH, b0);
    k_l2f<1><<<g2, 256, 0, stream>>>(W2, b2, m1fa, mdB, gate, qd,
                                     mn, mx, CH, b0);
  }

  k_final<<<(BATCH_N * OUT_N + 255) / 256, 256, 0, stream>>>(
      mn, mx, out, BATCH_N * OUT_N);
}